// Round 10
// baseline (376.973 us; speedup 1.0000x reference)
//
#include <hip/hip_runtime.h>
#include <math.h>
#include <stdint.h>

#define TL 128        // text length (m)
#define IL 100        // image length (n)
#define NP 112        // n padded (28 n-groups of 4)
#define DIM 768
#define NSEQ 228
#define KT 32         // K chunk (floats per row per chunk)
#define NT 1024       // 16 waves: 4 waves/SIMD
#define NWAVE 16
#define ITERS 50
// HARNESS NOTE: __builtin_amdgcn_mov_dpp / permlane*_swap kill this container
// before producing a verdict (rounds 1/2/6 vs 3/4/5 — 3-vs-3 isolation).
// Only __shfl_xor / MFMA / s_barrier / lgkm-waitcnt primitives below.
// Round-10: r9 showed conflicts are NOT the limiter (7.9M vs 9.7M, same dur).
// Cost is serialization: 4 barriers + 4 LDS round-trips/iter. This round: the
// delta path is fused into owners (in-wave shfl pre-reduce -> pq2[n][4] ->
// broadcast b128 read), removing 1 barrier + 1 round-trip + 77 wave-insts.

typedef float f32x4 __attribute__((ext_vector_type(4)));
typedef short short8 __attribute__((ext_vector_type(8)));

__device__ __forceinline__ uint16_t f2bf(float x) {
    union { float f; uint32_t u; } v; v.f = x;
    uint32_t r = v.u + 0x7FFFu + ((v.u >> 16) & 1u);   // RNE
    return (uint16_t)(r >> 16);
}
__device__ __forceinline__ float bf2f(uint16_t h) {
    union { float f; uint32_t u; } v; v.u = ((uint32_t)h) << 16;
    return v.f;
}

__device__ __forceinline__ float xorsum64(float x) {   // epilogue only
    x += __shfl_xor(x, 1);
    x += __shfl_xor(x, 2);
    x += __shfl_xor(x, 4);
    x += __shfl_xor(x, 8);
    x += __shfl_xor(x, 16);
    x += __shfl_xor(x, 32);
    return x;
}

// Barrier WITHOUT the vmcnt(0) drain __syncthreads() implies; prefetch loads
// stay in flight across chunk boundaries (only LDS ordering needed here).
__device__ __forceinline__ void gemm_barrier() {
    __builtin_amdgcn_sched_barrier(0);
    asm volatile("s_waitcnt lgkmcnt(0)" ::: "memory");
    __builtin_amdgcn_s_barrier();
    __builtin_amdgcn_sched_barrier(0);
}

// Round-4 lesson: buffer/array selection must be COMPILE-TIME (runtime pointer
// to register arrays -> scratch, 162 MB HBM writes). Macros take NAMED arrays.
#define CONVERT_STORE(vv, par) do {                                            \
    uint16_t* base_ = &u.stg[par][0];                                          \
    _Pragma("unroll")                                                          \
    for (int r = 0; r < 2; r++) if (act[r]) {                                  \
        float4 x = vv[r];                                                      \
        nrm[r] += x.x*x.x + x.y*x.y + x.z*x.z + x.w*x.w;                       \
        uint16_t h0 = f2bf(x.x), h1 = f2bf(x.y), h2 = f2bf(x.z), h3 = f2bf(x.w); \
        uint16_t l0 = f2bf(x.x - bf2f(h0)), l1 = f2bf(x.y - bf2f(h1));         \
        uint16_t l2 = f2bf(x.z - bf2f(h2)), l3 = f2bf(x.w - bf2f(h3));         \
        uint64_t hq  = (uint64_t)h0 | ((uint64_t)h1<<16) | ((uint64_t)h2<<32) | ((uint64_t)h3<<48); \
        uint64_t lq8 = (uint64_t)l0 | ((uint64_t)l1<<16) | ((uint64_t)l2<<32) | ((uint64_t)l3<<48); \
        *(uint64_t*)(base_ + off_hi[r])        = hq;                           \
        *(uint64_t*)(base_ + (off_hi[r] ^ 32)) = lq8;                          \
    }                                                                          \
} while (0)

#define PREFETCH(vv, cidx) do {                                                \
    _Pragma("unroll")                                                          \
    for (int r = 0; r < 2; r++) if (act[r])                                    \
        vv[r] = *(const float4*)(gp[r] + (cidx) * KT);                         \
} while (0)

// 16 waves: wave w owns m-tile wm = w>>1 (16 rows) x n-tiles 4wn..4wn+NQ-1.
#define MFMA_CHUNK(par) do {                                                   \
    const uint16_t* base_ = &u.stg[par][0];                                    \
    short8 ah, al, bh[4], bl[4];                                               \
    {                                                                          \
        int m = 16 * wm + lr;                                                  \
        int s = (lq + m + (m >> 3)) & 7;                                       \
        int ao = m * 64 + 8 * s;                                               \
        ah = *(const short8*)(base_ + ao);                                     \
        al = *(const short8*)(base_ + (ao ^ 32));                              \
    }                                                                          \
    _Pragma("unroll")                                                          \
    for (int q = 0; q < 4; q++) if (q < NQ) {                                  \
        int n  = 16 * (4*wn + q) + lr;                                         \
        int rr = TL + n;                                                       \
        int s  = (lq + rr + (rr >> 3)) & 7;                                    \
        int bo = rr * 64 + 8 * s;                                              \
        bh[q] = *(const short8*)(base_ + bo);                                  \
        bl[q] = *(const short8*)(base_ + (bo ^ 32));                           \
    }                                                                          \
    _Pragma("unroll")                                                          \
    for (int q = 0; q < 4; q++) if (q < NQ) {                                  \
        acc[q] = __builtin_amdgcn_mfma_f32_16x16x32_bf16(ah, bh[q], acc[q], 0, 0, 0); \
        acc[q] = __builtin_amdgcn_mfma_f32_16x16x32_bf16(ah, bl[q], acc[q], 0, 0, 0); \
        acc[q] = __builtin_amdgcn_mfma_f32_16x16x32_bf16(al, bh[q], acc[q], 0, 0, 0); \
    }                                                                          \
} while (0)

__global__ void __launch_bounds__(NT, 4)
WRA_ot_kernel(const float* __restrict__ seq,
              const int* __restrict__ txt_pad,
              const int* __restrict__ img_pad,
              const int* __restrict__ is_correct,
              float* __restrict__ out, int nblocks)
{
    __shared__ __align__(16) union {
        uint16_t stg[2][240 * 64];   // 61440 B  dbuf staging: rows 0..127 X, 128..239 Y
        float As[896 * 16];          // 57344 B  raw dot, IPOT-owner layout
        struct {                     // IPOT-loop reduction tables
            float pq2[NP * 4];       // qs pre-reduced partials: one b128 row per n
            float ps[TL * 29];       // s partials: ps[m*29 + nI] (odd stride)
        } ip;
    } u;
    __shared__ __align__(16) float sums[NSEQ];   // row sum-squares
    __shared__ __align__(16) float xm[TL];       // txt pad mask * 1e4
    __shared__ __align__(16) float ym[NP];       // img pad mask * 1e4
    __shared__ __align__(16) float inx[TL];      // inv norms
    __shared__ __align__(16) float iny[NP];
    __shared__ __align__(16) float sgf[TL];      // sigma result
    __shared__ float red[NWAVE];
    __shared__ int cnt[2];

    const int t    = threadIdx.x;
    const int b    = blockIdx.x;
    const int w    = t >> 6;
    const int lane = t & 63;

    // ---- phase 0: masks & lengths ----
    if (t < 2) cnt[t] = 0;
    if (t < NSEQ) sums[t] = 0.0f;
    __syncthreads();
    if (t < TL) {
        int p = txt_pad[b * TL + t] ? 1 : 0;
        xm[t] = p ? 1e4f : 0.0f;
        if (p) atomicAdd(&cnt[0], 1);
    } else if (t < TL + IL) {
        int p = img_pad[b * IL + (t - TL)] ? 1 : 0;
        ym[t - TL] = p ? 1e4f : 0.0f;
        if (p) atomicAdd(&cnt[1], 1);
    } else if (t < TL + NP) {
        ym[t - TL] = 1e4f;   // fake n = 100..111
    }

    // ---- GEMM: raw dot D[m,n] = sum_k X[m,k] Y[n,k] via split-bf16 MFMA ----
    const float* Xg = seq + (size_t)b * NSEQ * DIM;   // text rows 0..127
    const float* Yg = Xg + (size_t)TL * DIM;          // img rows 0..99

    // staging slots: 1824 float4 per chunk, slot f = t + 1024*r (r<2)
    const float* gp[2];
    int   off_hi[2];    // ushort offset within one staging buffer (hi half-quad)
    int   srow[2];
    bool  act[2];
    float nrm[2];
#pragma unroll
    for (int r = 0; r < 2; r++) {
        int f = t + NT * r;
        act[r] = (f < 1824);
        nrm[r] = 0.0f;
        int f2 = act[r] ? f : 0;
        bool isX = (f2 < 1024);
        int row = isX ? (f2 >> 3) : ((f2 - 1024) >> 3);
        int kc  = (f2 & 7) << 2;                  // k offset 0..28 (floats)
        gp[r] = (isX ? Xg : Yg) + row * DIM + kc;
        int rr = isX ? row : (TL + row);          // unified staging row 0..227
        srow[r] = rr;
        int q = (f2 & 7) >> 1;                    // logical hi quad 0..3
        int h = f2 & 1;                           // 8B half within quad
        int s = (q + rr + (rr >> 3)) & 7;         // physical slot (rotation)
        off_hi[r] = rr * 64 + 8 * s + 4 * h;      // lo half lives at off_hi ^ 32
    }
    {   // zero Y pad rows 100..111 (staging rows 228..239) in BOTH parities
        uint32_t* s32 = (uint32_t*)&u.stg[0][0];
        for (int i = t; i < 384 * 2; i += NT) {
            int par = (i < 384) ? 0 : 1;
            int off = i - par * 384;
            s32[par * 7680 + 228 * 32 + off] = 0;
        }
    }

    const int wm = w >> 1;            // m-tile 0..7
    const int wn = w & 1;
    const int NQ = wn ? 3 : 4;        // n-tiles 0..3 | 4..6
    f32x4 acc[4];
#pragma unroll
    for (int q = 0; q < 4; q++) acc[q] = (f32x4){0.f, 0.f, 0.f, 0.f};

    const int lr = lane & 15, lq = lane >> 4;

    // prologue: chunk0 -> buf0 (from va); vb holds chunk1; va refilled w/ chunk2
    float4 va[2], vb[2];
    PREFETCH(va, 0);
    PREFETCH(vb, 1);
    CONVERT_STORE(va, 0);
    PREFETCH(va, 2);
    gemm_barrier();   // buf0 ready (also covers zero-pad + phase-0 LDS writes)

    // steady state, UNROLLED x2 so buffer/array selection is compile-time
#pragma unroll 1
    for (int cc = 0; cc < 24; cc += 2) {
        {   // chunk cc (even, buf0; chunk cc+1 data sits in vb)
            if (cc < 23) {
                CONVERT_STORE(vb, 1);
                if (cc < 21) PREFETCH(vb, cc + 3);
            }
            MFMA_CHUNK(0);
            gemm_barrier();
        }
        {   // chunk cc+1 (odd, buf1; chunk cc+2 data sits in va)
            if (cc + 1 < 23) {
                CONVERT_STORE(va, 0);
                if (cc + 1 < 21) PREFETCH(va, cc + 4);
            }
            MFMA_CHUNK(1);
            gemm_barrier();
        }
    }

    // (final gemm_barrier drained all frag reads -> safe to overwrite stg)
#pragma unroll
    for (int r = 0; r < 2; r++) if (act[r]) atomicAdd(&sums[srow[r]], nrm[r]);
    // scatter raw dots into IPOT-owner layout. Owner tp = (m&31) + 32*(n>>2)
    // holds m-slot ii = m>>5, n-slot jj = n&3:
    //   word = tp*16 + ((jj ^ (tp&3))<<2) + ii     (one-time; conflicts amortized)
#pragma unroll
    for (int q = 0; q < 4; q++) if (q < NQ)
#pragma unroll
        for (int rg = 0; rg < 4; rg++) {
            int m = 16 * wm + 4*lq + rg;           // D row = quad*4+reg
            int n = 16 * (4*wn + q) + lr;          // D col = lane&15
            int tp = (m & 31) + ((n >> 2) << 5);
            int word = (tp << 4) + (((n & 3) ^ (tp & 3)) << 2) + (m >> 5);
            u.As[word] = acc[q][rg];
        }
    __syncthreads();
    if (t < TL)            inx[t]      = 1.0f / fmaxf(sqrtf(sums[t]), 1e-5f);
    else if (t < NSEQ)     iny[t - TL] = 1.0f / fmaxf(sqrtf(sums[t]), 1e-5f);
    else if (t < TL + NP)  iny[t - TL] = 1.0f;
    __syncthreads();

    // ---- IPOT: thread t = mI + 32*nI owns m in {mI+32i}, n = 4nI..+3 ----
    const float xlen = (float)(TL - cnt[0]);
    const float ylen = (float)(IL - cnt[1]);
    const int mI = t & 31;
    const int nI = t >> 5;               // 0..31; active < 28 (waves 0..13, uniform)
    const bool activeN = (nI < 28);

    float rx[4], xmv[4], ry[4], ymv[4];
    {
#pragma unroll
        for (int i = 0; i < 4; i++) {
            rx[i]  = inx[mI + 32*i];
            xmv[i] = xm[mI + 32*i];
        }
        if (activeN) {
            float4 c0 = *(const float4*)&iny[4*nI];   // broadcast within half-wave
            ry[0]=c0.x; ry[1]=c0.y; ry[2]=c0.z; ry[3]=c0.w;
            float4 d0 = *(const float4*)&ym[4*nI];
            ymv[0]=d0.x; ymv[1]=d0.y; ymv[2]=d0.z; ymv[3]=d0.w;
        } else {
#pragma unroll
            for (int j = 0; j < 4; j++) { ry[j] = 1.0f; ymv[j] = 1e4f; }
        }
    }

    float aa[4][4], qq[4][4];   // [j = n-slot][i = m-slot (m = mI+32i)]
    if (activeN) {
#pragma unroll
        for (int j = 0; j < 4; j++) {
            float4 d0 = *(const float4*)&u.As[(t << 4) + ((j ^ (t & 3)) << 2)];
            float dv[4] = {d0.x, d0.y, d0.z, d0.w};
#pragma unroll
            for (int i = 0; i < 4; i++) {
                bool pad = (xmv[i] > 0.0f) || (ymv[j] > 0.0f);
                float cc = pad ? 0.0f : (1.0f - dv[i] * rx[i] * ry[j]);
                float av = pad ? 0.0f : expf(-2.0f * cc);
                aa[j][i] = av; qq[j][i] = av;
            }
        }
    } else {
#pragma unroll
        for (int j = 0; j < 4; j++)
#pragma unroll
            for (int i = 0; i < 4; i++) { aa[j][i] = 0.0f; qq[j][i] = 0.0f; }
    }
    __syncthreads();   // As reads done before ip tables (union overlay) are written

    float sg[4];
#pragma unroll
    for (int i = 0; i < 4; i++) sg[i] = (xmv[i] > 0.0f) ? 0.0f : (1.0f / xlen);

    float dl[4];
    for (int it = 0; it < ITERS; ++it) {
        // phase 1: qs partials, pre-reduced in-wave (4 independent shfl chains
        // pipeline) -> pq2[n][4]; lanes mI%8==0 write (8 distinct banks/inst)
        if (activeN) {
#pragma unroll
            for (int j = 0; j < 4; j++) {
                float pj = qq[j][0]*sg[0] + qq[j][1]*sg[1] + qq[j][2]*sg[2] + qq[j][3]*sg[3];
                pj += __shfl_xor(pj, 1);
                pj += __shfl_xor(pj, 2);
                pj += __shfl_xor(pj, 4);
                if ((mI & 7) == 0)
                    u.ip.pq2[((4*nI + j) << 2) + (mI >> 3)] = pj;
            }
        }
        __syncthreads();   // B1: pq2 ready
        // phase 2+3 fused: owners read pq2 rows as BROADCAST b128 (all mI lanes
        // same addr -> free), compute delta redundantly, write s partials.
        if (activeN) {
#pragma unroll
            for (int j = 0; j < 4; j++) {
                float4 p4 = *(const float4*)&u.ip.pq2[(4*nI + j) << 2];
                float qs = (p4.x + p4.y) + (p4.z + p4.w);
                dl[j] = __builtin_amdgcn_rcpf(ylen * qs + ymv[j]);
            }
#pragma unroll
            for (int i = 0; i < 4; i++) {
                float s = dl[0]*qq[0][i] + dl[1]*qq[1][i] + dl[2]*qq[2][i] + dl[3]*qq[3][i];
                u.ip.ps[(mI + 32*i) * 29 + nI] = s;   // bank = 29*mI+nI: bijective
            }
        } else {
            dl[0]=dl[1]=dl[2]=dl[3]=0.0f;   // keep NaN out of epilogue products
        }
        __syncthreads();   // B2: ps ready
        // phase 4: s reduce, 4 threads/m (7 loads + 2 shfl), sigma -> sgf
        if (t < 4 * TL) {
            int m = t >> 2, qh = t & 3;
            const float* row = &u.ip.ps[m * 29 + 7 * qh];
            float s = ((row[0] + row[1]) + (row[2] + row[3]))
                    + ((row[4] + row[5]) + row[6]);
            s += __shfl_xor(s, 1);
            s += __shfl_xor(s, 2);
            if (qh == 0) sgf[m] = __builtin_amdgcn_rcpf(xlen * s + xm[m]);
        }
        __syncthreads();   // B3: sgf ready
        // phase 5: owners read sigma (4x b32, broadcast across nI) + update
        sg[0] = sgf[mI];
        sg[1] = sgf[mI + 32];
        sg[2] = sgf[mI + 64];
        sg[3] = sgf[mI + 96];
        if (it < ITERS - 1) {
#pragma unroll
            for (int j = 0; j < 4; j++) {
                float dj = dl[j];
#pragma unroll
                for (int i = 0; i < 4; i++)
                    qq[j][i] = (qq[j][i] * aa[j][i]) * (dj * sg[i]);
            }
        }
    }

    // ot = sum C^T (.) T_50 ;  c = -0.5*ln(a) on non-pad entries
    float local = 0.0f;
#pragma unroll
    for (int j = 0; j < 4; j++)
#pragma unroll
        for (int i = 0; i < 4; i++) {
            float av = aa[j][i];
            float cc = (av > 0.0f) ? (-0.5f * logf(av)) : 0.0f;
            local += cc * qq[j][i] * (dl[j] * sg[i]);
        }
    local = xorsum64(local);
    if (lane == 0) red[w] = local;
    __syncthreads();
    if (t == 0) {
        float tot = 0.0f;
#pragma unroll
        for (int k = 0; k < NWAVE; k++) tot += red[k];
        float sgn = (is_correct[b] == 1) ? 1.0f : -1.0f;
        atomicAdd(out, sgn * tot / (float)nblocks);
    }
}

extern "C" void kernel_launch(void* const* d_in, const int* in_sizes, int n_in,
                              void* d_out, int out_size, void* d_ws, size_t ws_size,
                              hipStream_t stream) {
    const float* seq   = (const float*)d_in[0];
    const int* txt_pad = (const int*)d_in[3];
    const int* img_pad = (const int*)d_in[4];
    const int* is_corr = (const int*)d_in[5];
    float* out = (float*)d_out;
    const int B = in_sizes[5];

    hipMemsetAsync(out, 0, sizeof(float), stream);
    WRA_ot_kernel<<<B, NT, 0, stream>>>(seq, txt_pad, img_pad, is_corr, out, B);
}

// Round 12
// 352.355 us; speedup vs baseline: 1.0699x; 1.0699x over previous
//
#include <hip/hip_runtime.h>
#include <math.h>
#include <stdint.h>

#define TL 128        // text length (m)
#define IL 100        // image length (n)
#define NP 112        // n padded (16 nI groups x 7 k)
#define DIM 768
#define NSEQ 228
#define KT 32         // K chunk (floats per row per chunk)
#define NT 512        // 8 waves (round-11: back to 512 w/ cooperative tables;
                      // at NT=1024 half the waves idled through phases 2/4)
#define NWAVE 8
#define ITERS 50
// HARNESS NOTE (r11): "container failed twice" hit a kernel with NO exotic
// primitives -> infra flake is a real failure mode (r9 logged a 1423s npz
// push). This is a verbatim resubmission of the r11 kernel (audited: uniform
// barriers, all LDS indices in bounds, GEMM identical to the r5 pass).
// Round-10 lesson: a barrier costs ~<300cyc; dependent shfl chains ~37cyc each
// on the LDS pipe — do NOT trade barriers for shfl chains.
// Round-9 lesson: bank conflicts at this scale are ~600cyc/CU/iter — noise.
// Round-11 mechanism: phase occupancy. Uniform 4m x 7n ownership (n = nI+16k)
// -> zero idle threads in phases 1/3/5, 7/8 waves in ph2, 8/8 in ph4.

typedef float f32x4 __attribute__((ext_vector_type(4)));
typedef short short8 __attribute__((ext_vector_type(8)));

__device__ __forceinline__ uint16_t f2bf(float x) {
    union { float f; uint32_t u; } v; v.f = x;
    uint32_t r = v.u + 0x7FFFu + ((v.u >> 16) & 1u);   // RNE
    return (uint16_t)(r >> 16);
}
__device__ __forceinline__ float bf2f(uint16_t h) {
    union { float f; uint32_t u; } v; v.u = ((uint32_t)h) << 16;
    return v.f;
}

__device__ __forceinline__ float xorsum64(float x) {   // epilogue only
    x += __shfl_xor(x, 1);
    x += __shfl_xor(x, 2);
    x += __shfl_xor(x, 4);
    x += __shfl_xor(x, 8);
    x += __shfl_xor(x, 16);
    x += __shfl_xor(x, 32);
    return x;
}

// Barrier WITHOUT the vmcnt(0) drain __syncthreads() implies; prefetch loads
// stay in flight across chunk boundaries (only LDS ordering needed here).
__device__ __forceinline__ void gemm_barrier() {
    __builtin_amdgcn_sched_barrier(0);
    asm volatile("s_waitcnt lgkmcnt(0)" ::: "memory");
    __builtin_amdgcn_s_barrier();
    __builtin_amdgcn_sched_barrier(0);
}

// Round-4 lesson: buffer/array selection must be COMPILE-TIME (runtime pointer
// to register arrays -> scratch, 162 MB HBM writes). Macros take NAMED arrays.
#define CONVERT_STORE(vv, par) do {                                            \
    uint16_t* base_ = &u.stg[par][0];                                          \
    _Pragma("unroll")                                                          \
    for (int r = 0; r < 4; r++) if (act[r]) {                                  \
        float4 x = vv[r];                                                      \
        nrm[r] += x.x*x.x + x.y*x.y + x.z*x.z + x.w*x.w;                       \
        uint16_t h0 = f2bf(x.x), h1 = f2bf(x.y), h2 = f2bf(x.z), h3 = f2bf(x.w); \
        uint16_t l0 = f2bf(x.x - bf2f(h0)), l1 = f2bf(x.y - bf2f(h1));         \
        uint16_t l2 = f2bf(x.z - bf2f(h2)), l3 = f2bf(x.w - bf2f(h3));         \
        uint64_t hq  = (uint64_t)h0 | ((uint64_t)h1<<16) | ((uint64_t)h2<<32) | ((uint64_t)h3<<48); \
        uint64_t lq8 = (uint64_t)l0 | ((uint64_t)l1<<16) | ((uint64_t)l2<<32) | ((uint64_t)l3<<48); \
        *(uint64_t*)(base_ + off_hi[r])        = hq;                           \
        *(uint64_t*)(base_ + (off_hi[r] ^ 32)) = lq8;                          \
    }                                                                          \
} while (0)

#define PREFETCH(vv, cidx) do {                                                \
    _Pragma("unroll")                                                          \
    for (int r = 0; r < 4; r++) if (act[r])                                    \
        vv[r] = *(const float4*)(gp[r] + (cidx) * KT);                         \
} while (0)

#define MFMA_CHUNK(par) do {                                                   \
    const uint16_t* base_ = &u.stg[par][0];                                    \
    short8 ah[2], al[2], bh[4], bl[4];                                         \
    _Pragma("unroll")                                                          \
    for (int a = 0; a < 2; a++) {                                              \
        int m = 16 * (2*wm + a) + lr;                                          \
        int s = (lq + m + (m >> 3)) & 7;                                       \
        int ao = m * 64 + 8 * s;                                               \
        ah[a] = *(const short8*)(base_ + ao);                                  \
        al[a] = *(const short8*)(base_ + (ao ^ 32));                           \
    }                                                                          \
    _Pragma("unroll")                                                          \
    for (int q = 0; q < 4; q++) if (q < NQ) {                                  \
        int n  = 16 * (4*wn + q) + lr;                                         \
        int rr = TL + n;                                                       \
        int s  = (lq + rr + (rr >> 3)) & 7;                                    \
        int bo = rr * 64 + 8 * s;                                              \
        bh[q] = *(const short8*)(base_ + bo);                                  \
        bl[q] = *(const short8*)(base_ + (bo ^ 32));                           \
    }                                                                          \
    _Pragma("unroll")                                                          \
    for (int a = 0; a < 2; a++)                                                \
        _Pragma("unroll")                                                      \
        for (int q = 0; q < 4; q++) if (q < NQ) {                              \
            acc[a][q] = __builtin_amdgcn_mfma_f32_16x16x32_bf16(ah[a], bh[q], acc[a][q], 0, 0, 0); \
            acc[a][q] = __builtin_amdgcn_mfma_f32_16x16x32_bf16(ah[a], bl[q], acc[a][q], 0, 0, 0); \
            acc[a][q] = __builtin_amdgcn_mfma_f32_16x16x32_bf16(al[a], bh[q], acc[a][q], 0, 0, 0); \
        }                                                                      \
} while (0)

__global__ void __launch_bounds__(NT, 2)
WRA_ot_kernel(const float* __restrict__ seq,
              const int* __restrict__ txt_pad,
              const int* __restrict__ img_pad,
              const int* __restrict__ is_correct,
              float* __restrict__ out, int nblocks)
{
    __shared__ __align__(16) union {
        uint16_t stg[2][240 * 64];   // 61440 B  dbuf staging: rows 0..127 X, 128..239 Y
        float As[NT * 29];           // 59392 B  raw dot, owner rows (stride 29)
        struct {                     // IPOT-loop reduction tables (24000 B)
            float pq[NP * 33];       // qs partials: pq[n*33 + mI]
            float ps[TL * 17];       // s partials:  ps[m*17 + nI]
            float dlv[TL];           // delta result
        } ip;
    } u;
    __shared__ __align__(16) float sums[NSEQ];   // row sum-squares
    __shared__ __align__(16) float xm[TL];       // txt pad mask * 1e4
    __shared__ __align__(16) float ym[NP];       // img pad mask * 1e4
    __shared__ __align__(16) float inx[TL];      // inv norms
    __shared__ __align__(16) float iny[NP];
    __shared__ __align__(16) float sgf[TL];      // sigma result
    __shared__ float red[NWAVE];
    __shared__ int cnt[2];
    // LDS total: 61440 + 912+512+448+512+448+512+32+8 = 64824 B <= 64 KiB

    const int t    = threadIdx.x;
    const int b    = blockIdx.x;
    const int w    = t >> 6;
    const int lane = t & 63;

    // ---- phase 0: masks & lengths ----
    if (t < 2) cnt[t] = 0;
    if (t < NSEQ) sums[t] = 0.0f;
    __syncthreads();
    if (t < TL) {
        int p = txt_pad[b * TL + t] ? 1 : 0;
        xm[t] = p ? 1e4f : 0.0f;
        if (p) atomicAdd(&cnt[0], 1);
    } else if (t < TL + IL) {
        int p = img_pad[b * IL + (t - TL)] ? 1 : 0;
        ym[t - TL] = p ? 1e4f : 0.0f;
        if (p) atomicAdd(&cnt[1], 1);
    } else if (t < TL + NP) {
        ym[t - TL] = 1e4f;   // fake n = 100..111
    }

    // ---- GEMM: raw dot D[m,n] = sum_k X[m,k] Y[n,k] via split-bf16 MFMA ----
    // (r5-proven 8-wave version, verbatim)
    const float* Xg = seq + (size_t)b * NSEQ * DIM;   // text rows 0..127
    const float* Yg = Xg + (size_t)TL * DIM;          // img rows 0..99

    const float* gp[4];
    int   off_hi[4];
    int   srow[4];
    bool  act[4];
    float nrm[4];
#pragma unroll
    for (int r = 0; r < 4; r++) {
        int f = t + NT * r;
        act[r] = (f < 1824);
        nrm[r] = 0.0f;
        int f2 = act[r] ? f : 0;
        bool isX = (f2 < 1024);
        int row = isX ? (f2 >> 3) : ((f2 - 1024) >> 3);
        int kc  = (f2 & 7) << 2;
        gp[r] = (isX ? Xg : Yg) + row * DIM + kc;
        int rr = isX ? row : (TL + row);
        srow[r] = rr;
        int q = (f2 & 7) >> 1;
        int h = f2 & 1;
        int s = (q + rr + (rr >> 3)) & 7;
        off_hi[r] = rr * 64 + 8 * s + 4 * h;
    }
    {   // zero Y pad rows 100..111 (staging rows 228..239) in BOTH parities
        uint32_t* s32 = (uint32_t*)&u.stg[0][0];
        for (int i = t; i < 384 * 2; i += NT) {
            int par = (i < 384) ? 0 : 1;
            int off = i - par * 384;
            s32[par * 7680 + 228 * 32 + off] = 0;
        }
    }

    const int wm = w >> 1;
    const int wn = w & 1;
    const int NQ = wn ? 3 : 4;
    f32x4 acc[2][4];
#pragma unroll
    for (int a = 0; a < 2; a++)
#pragma unroll
        for (int q = 0; q < 4; q++) acc[a][q] = (f32x4){0.f, 0.f, 0.f, 0.f};

    const int lr = lane & 15, lq = lane >> 4;

    float4 va[4], vb[4];
    PREFETCH(va, 0);
    PREFETCH(vb, 1);
    CONVERT_STORE(va, 0);
    PREFETCH(va, 2);
    gemm_barrier();

#pragma unroll 1
    for (int cc = 0; cc < 24; cc += 2) {
        {
            if (cc < 23) {
                CONVERT_STORE(vb, 1);
                if (cc < 21) PREFETCH(vb, cc + 3);
            }
            MFMA_CHUNK(0);
            gemm_barrier();
        }
        {
            if (cc + 1 < 23) {
                CONVERT_STORE(va, 0);
                if (cc + 1 < 21) PREFETCH(va, cc + 4);
            }
            MFMA_CHUNK(1);
            gemm_barrier();
        }
    }

#pragma unroll
    for (int r = 0; r < 4; r++) if (act[r]) atomicAdd(&sums[srow[r]], nrm[r]);
    // scatter into owner rows: owner t' = (m&31) + 32*(n&15); cell = 4*(n>>4) + (m>>5)
    // (one-time; write conflicts amortized over 50 iters)
#pragma unroll
    for (int a = 0; a < 2; a++)
#pragma unroll
        for (int q = 0; q < 4; q++) if (q < NQ)
#pragma unroll
            for (int rg = 0; rg < 4; rg++) {
                int m = 16 * (2*wm + a) + 4*lq + rg;
                int n = 16 * (4*wn + q) + lr;
                int tp = (m & 31) + ((n & 15) << 5);
                u.As[tp * 29 + ((n >> 4) << 2) + (m >> 5)] = acc[a][q][rg];
            }
    __syncthreads();
    if (t < TL)            inx[t]      = 1.0f / fmaxf(sqrtf(sums[t]), 1e-5f);
    else if (t < NSEQ)     iny[t - TL] = 1.0f / fmaxf(sqrtf(sums[t]), 1e-5f);
    else if (t < TL + NP)  iny[t - TL] = 1.0f;
    __syncthreads();

    // ---- IPOT: thread t owns m in {mI+32i} (i=0..3), n in {nI+16k} (k=0..6) ----
    // mI = t&31, nI = t>>5 in 0..15 -> ALL 512 threads own real cells (uniform).
    const float xlen = (float)(TL - cnt[0]);
    const float ylen = (float)(IL - cnt[1]);
    const int mI = t & 31;
    const int nI = t >> 5;

    float rx[4], xmv[4], ry[7], ymv[7];
#pragma unroll
    for (int i = 0; i < 4; i++) {
        rx[i]  = inx[mI + 32*i];
        xmv[i] = xm[mI + 32*i];
    }
#pragma unroll
    for (int k = 0; k < 7; k++) {
        ry[k]  = iny[nI + 16*k];   // broadcast per half-wave
        ymv[k] = ym[nI + 16*k];
    }

    float aa[7][4], qq[7][4];   // [k = n-slot (n=nI+16k)][i = m-slot (m=mI+32i)]
#pragma unroll
    for (int k = 0; k < 7; k++) {
        // 4 b32 reads: bank = 29t + 4k + i -> bijective per half-wave, 2-way: free
        const float* rowp = &u.As[t * 29 + 4*k];
#pragma unroll
        for (int i = 0; i < 4; i++) {
            float dvv = rowp[i];
            bool pad = (xmv[i] > 0.0f) || (ymv[k] > 0.0f);
            float ccv = pad ? 0.0f : (1.0f - dvv * rx[i] * ry[k]);
            float av  = pad ? 0.0f : expf(-2.0f * ccv);
            aa[k][i] = av; qq[k][i] = av;
        }
    }
    __syncthreads();   // As reads done before ip tables (union overlay) written

    float sg[4];
#pragma unroll
    for (int i = 0; i < 4; i++) sg[i] = (xmv[i] > 0.0f) ? 0.0f : (1.0f / xlen);

    float dl[7];
    for (int it = 0; it < ITERS; ++it) {
        // phase 1 (all 8 waves): qs partials -> pq[n*33 + mI]
        // bank = n + mI: bijective per half-wave, 2-way across halves: free
#pragma unroll
        for (int k = 0; k < 7; k++) {
            float pj = qq[k][0]*sg[0] + qq[k][1]*sg[1] + qq[k][2]*sg[2] + qq[k][3]*sg[3];
            u.ip.pq[(nI + 16*k) * 33 + mI] = pj;
        }
        __syncthreads();   // B1
        // phase 2 (7 of 8 waves): qs reduce, 4 thr/n (8 loads + 2 shfl) -> dlv
        if (t < 4 * NP) {
            int n = t >> 2, qh = t & 3;
            const float* row = &u.ip.pq[n * 33 + 8 * qh];
            float s = ((row[0] + row[1]) + (row[2] + row[3]))
                    + ((row[4] + row[5]) + (row[6] + row[7]));
            s += __shfl_xor(s, 1);
            s += __shfl_xor(s, 2);
            if (qh == 0) u.ip.dlv[n] = __builtin_amdgcn_rcpf(ylen * s + ym[n]);
        }
        __syncthreads();   // B2
        // phase 3 (all waves, uniform): read delta (broadcast), s partials -> ps
        // ps bank = 17*(mI+32i) + nI = (17mI + nI): bijective per half-wave: free
#pragma unroll
        for (int k = 0; k < 7; k++) dl[k] = u.ip.dlv[nI + 16*k];
#pragma unroll
        for (int i = 0; i < 4; i++) {
            float s = dl[0]*qq[0][i] + dl[1]*qq[1][i] + dl[2]*qq[2][i]
                    + dl[3]*qq[3][i] + dl[4]*qq[4][i] + dl[5]*qq[5][i]
                    + dl[6]*qq[6][i];
            u.ip.ps[(mI + 32*i) * 17 + nI] = s;
        }
        __syncthreads();   // B3
        // phase 4 (ALL 512 threads): s reduce, 4 thr/m (4 loads + 2 shfl) -> sgf
        {
            int m = t >> 2, qh = t & 3;
            const float* row = &u.ip.ps[m * 17 + 4 * qh];
            float s = (row[0] + row[1]) + (row[2] + row[3]);
            s += __shfl_xor(s, 1);
            s += __shfl_xor(s, 2);
            if (qh == 0) sgf[m] = __builtin_amdgcn_rcpf(xlen * s + xm[m]);
        }
        __syncthreads();   // B4
        // phase 5 (all waves): read sigma (bijective per half-wave: free)
        sg[0] = sgf[mI];
        sg[1] = sgf[mI + 32];
        sg[2] = sgf[mI + 64];
        sg[3] = sgf[mI + 96];
        if (it < ITERS - 1) {
#pragma unroll
            for (int k = 0; k < 7; k++) {
                float dk = dl[k];
#pragma unroll
                for (int i = 0; i < 4; i++)
                    qq[k][i] = (qq[k][i] * aa[k][i]) * (dk * sg[i]);
            }
        }
    }

    // ot = sum C^T (.) T_50 ;  c = -0.5*ln(a) on non-pad entries
    float local = 0.0f;
#pragma unroll
    for (int k = 0; k < 7; k++)
#pragma unroll
        for (int i = 0; i < 4; i++) {
            float av = aa[k][i];
            float ccv = (av > 0.0f) ? (-0.5f * logf(av)) : 0.0f;
            local += ccv * qq[k][i] * (dl[k] * sg[i]);
        }
    local = xorsum64(local);
    if (lane == 0) red[w] = local;
    __syncthreads();
    if (t == 0) {
        float tot = 0.0f;
#pragma unroll
        for (int k = 0; k < NWAVE; k++) tot += red[k];
        float sgn = (is_correct[b] == 1) ? 1.0f : -1.0f;
        atomicAdd(out, sgn * tot / (float)nblocks);
    }
}

extern "C" void kernel_launch(void* const* d_in, const int* in_sizes, int n_in,
                              void* d_out, int out_size, void* d_ws, size_t ws_size,
                              hipStream_t stream) {
    const float* seq   = (const float*)d_in[0];
    const int* txt_pad = (const int*)d_in[3];
    const int* img_pad = (const int*)d_in[4];
    const int* is_corr = (const int*)d_in[5];
    float* out = (float*)d_out;
    const int B = in_sizes[5];

    hipMemsetAsync(out, 0, sizeof(float), stream);
    WRA_ot_kernel<<<B, NT, 0, stream>>>(seq, txt_pad, img_pad, is_corr, out, B);
}